// Round 6
// baseline (18210.365 us; speedup 1.0000x reference)
//
#include <hip/hip_runtime.h>

// GLIF recurrent network: T=8192 sequential steps, N=1024 neurons.
// 32 blocks x 320 threads: 4 COMPUTE waves + 1 PUBLISHER wave.
//   Compute waves: poll tagged u64s (4/thread, private per-block copy),
//     stage to LDS, 128 MACs/lane, reduce -> red[][]. They NEVER store to
//     global, so their poll vmcnt(0) waits on poll loads only (in-order
//     vmcnt retirement would otherwise drain stores first - R4's defect).
//   Publisher wave: after B2 reads red, does the GLIF elementwise update,
//     fans out tagged I_add to all 32 consumer-private copies, writes
//     vs/spikes, prefetches x. All stores fire-and-forget; its own vmcnt
//     waits happen a full step later (instant).
// Entry: u64 = (tag=step)<<32 | f32 bits, double-buffered by step parity.

#define T_STEPS 8192
#define N_NEUR  1024
#define NBLK    32
#define TPB     320
#define PSTRIDE (NBLK * N_NEUR)          // u64 entries per parity (32 copies)

typedef unsigned long long ull;

__global__ void glif_init(ull* __restrict__ buf) {
    int i = blockIdx.x * blockDim.x + threadIdx.x;
    if (i < PSTRIDE) {
        buf[i] = 0ULL;                                // S_0: value 0.0f, tag 0
    } else if (i < 2 * PSTRIDE) {
        buf[i] = 0xFFFFFFFF00000000ULL;               // odd parity: invalid tag
    }
}

__launch_bounds__(TPB, 1)
__global__ void glif_main(const float* __restrict__ x_in,
                          const float* __restrict__ w_p,
                          const float* __restrict__ E_L_p,
                          const float* __restrict__ tau_m_p,
                          const float* __restrict__ G_p,
                          const float* __restrict__ R_I_p,
                          const float* __restrict__ f_v_p,
                          const float* __restrict__ f_I_p,
                          const float* __restrict__ dths_p,
                          const float* __restrict__ b_s_p,
                          const float* __restrict__ a_v_p,
                          const float* __restrict__ b_v_p,
                          const float* __restrict__ th_inf_p,
                          const float* __restrict__ dV_p,
                          const float* __restrict__ I_A_p,
                          float* __restrict__ out,
                          ull* __restrict__ buf) {
    const int tid  = threadIdx.x;
    const int wv   = tid >> 6;                 // 0..3 compute, 4 publisher
    const int lane = tid & 63;

    __shared__ float ix[N_NEUR];               // staged I_add for this step
    __shared__ float red[4][32];               // per-compute-wave partials

    float* __restrict__ vs_out = out;
    float* __restrict__ sp_out = out + (size_t)T_STEPS * N_NEUR;

    if (wv < 4) {
        // ================= COMPUTE WAVES (tid 0..255) =================
        const int colL  = lane & 31;
        const int col   = blockIdx.x * 32 + colL;
        const int ibase = wv * 256 + (lane >> 5) * 128;   // 128 FMA rows

        float wreg[128];
#pragma unroll
        for (int j = 0; j < 128; ++j) {
            int r = ibase + j;
            float wval = w_p[(size_t)r * N_NEUR + col];
            wreg[j] = (r == col) ? 0.0f : wval;   // zero diagonal
        }

        for (int t = 0; t < T_STEPS; ++t) {
            // poll 4 tagged u64 (private copy): 4 loads, ONE vmcnt(0), check.
            // No stores ever outstanding in these waves -> pure load latency.
            const ull* src = buf + (size_t)(t & 1) * PSTRIDE
                                 + (size_t)blockIdx.x * N_NEUR + tid * 4;
            ull u0, u1, u2, u3;
            const unsigned ut = (unsigned)t;
            for (;;) {
                asm volatile(
                    "global_load_dwordx2 %0, %4, off sc0 sc1\n\t"
                    "global_load_dwordx2 %1, %4, off offset:8 sc0 sc1\n\t"
                    "global_load_dwordx2 %2, %4, off offset:16 sc0 sc1\n\t"
                    "global_load_dwordx2 %3, %4, off offset:24 sc0 sc1\n\t"
                    "s_waitcnt vmcnt(0)"
                    : "=&v"(u0), "=&v"(u1), "=&v"(u2), "=&v"(u3)
                    : "v"(src)
                    : "memory");
                bool ok = ((unsigned)(u0 >> 32) == ut) & ((unsigned)(u1 >> 32) == ut) &
                          ((unsigned)(u2 >> 32) == ut) & ((unsigned)(u3 >> 32) == ut);
                if (ok) break;
            }
            ((float4*)ix)[tid] = make_float4(__uint_as_float((unsigned)u0),
                                             __uint_as_float((unsigned)u1),
                                             __uint_as_float((unsigned)u2),
                                             __uint_as_float((unsigned)u3));

            // B1: ix staged (lgkm-only wait, no vmcnt drain)
            asm volatile("s_waitcnt lgkmcnt(0)" ::: "memory");
            __builtin_amdgcn_s_barrier();
            __builtin_amdgcn_sched_barrier(0);

            // 128 MACs, 4 independent chains
            float s0 = 0.f, s1 = 0.f, s2 = 0.f, s3 = 0.f;
            const float4* q4 = (const float4*)(ix + ibase);
#pragma unroll
            for (int m = 0; m < 32; ++m) {
                float4 q = q4[m];
                s0 = fmaf(wreg[4 * m + 0], q.x, s0);
                s1 = fmaf(wreg[4 * m + 1], q.y, s1);
                s2 = fmaf(wreg[4 * m + 2], q.z, s2);
                s3 = fmaf(wreg[4 * m + 3], q.w, s3);
            }
            float acc = (s0 + s1) + (s2 + s3);
            acc += __shfl_xor(acc, 32, 64);        // fold the two halves
            if (lane < 32) red[wv][colL] = acc;

            // B2: red ready
            asm volatile("s_waitcnt lgkmcnt(0)" ::: "memory");
            __builtin_amdgcn_s_barrier();
            __builtin_amdgcn_sched_barrier(0);
            // loop straight back to polling t+1
        }
    } else {
        // ================= PUBLISHER WAVE (tid 256..319) =================
        const int h    = lane >> 5;            // 0/1: copy-half (phase C redundant)
        const int colL = lane & 31;
        const int col  = blockIdx.x * 32 + colL;

        const float E_L     = E_L_p[col];
        const float inv_tau = 1.0f / tau_m_p[col];
        const float Gc      = G_p[col];
        const float R_I     = R_I_p[col];
        const float f_v     = f_v_p[col];
        const float om_fI   = 1.0f - f_I_p[col];
        const float dths    = dths_p[col];
        const float om_bs   = 1.0f - b_s_p[col];
        const float a_v     = a_v_p[col];
        const float b_v     = b_v_p[col];
        const float th_inf  = th_inf_p[col];
        const float dV      = dV_p[col];
        const float I_A     = I_A_p[col];

        float v = E_L, th_s = 30.0f, th_v = 1.0f, I_own = 0.0f;
        float xnext = x_in[col];               // x for t=0

        for (int t = 0; t < T_STEPS; ++t) {
            __builtin_amdgcn_s_barrier();      // B1 (nothing to wait on)
            __builtin_amdgcn_s_barrier();      // B2: red now ready
            __builtin_amdgcn_sched_barrier(0);

            float xt = xnext;
            float I = (red[0][colL] + red[1][colL]) + (red[2][colL] + red[3][colL])
                      + 0.85f * xt;
            float v_next = v + (I * R_I - Gc * (v - E_L)) * inv_tau;
            float thr = th_s + th_v;
            float z = v_next - thr;
            float soft = 1.0f / (1.0f + __expf(-z));   // surrogate spike
            I_own = om_fI * I_own + soft * I_A;

            // fan-out publish FIRST: half h serves copies [16h, 16h+16)
            ull pk = ((ull)(unsigned)(t + 1) << 32) | (ull)__float_as_uint(I_own);
            ull* dst = buf + (size_t)((t + 1) & 1) * PSTRIDE
                           + (size_t)(h * 16) * N_NEUR + col;
#pragma unroll
            for (int k = 0; k < 16; ++k) {
                __hip_atomic_store(dst + (size_t)k * N_NEUR, pk,
                                   __ATOMIC_RELAXED, __HIP_MEMORY_SCOPE_AGENT);
            }

            // state update + outputs + x-prefetch (all off the publish path;
            // stores/loads retire long before their next vmcnt wait)
            bool  sp = (v_next >= thr);                 // hard spike
            float v_reset = E_L + f_v * (v - E_L) - dV;
            float v_new = sp ? v_reset : v_next;
            th_s = om_bs * th_s + (sp ? dths : 0.0f);
            float d_thv = a_v * (v_new - E_L) - b_v * (th_v - th_inf);
            th_v = th_v + (sp ? 0.0f : d_thv);
            v = v_new;

            if (h == 0) {
                __builtin_nontemporal_store(v_new, &vs_out[(size_t)t * N_NEUR + col]);
                __builtin_nontemporal_store(soft, &sp_out[(size_t)t * N_NEUR + col]);
            }
            int tn = (t + 1 < T_STEPS) ? (t + 1) : t;
            xnext = x_in[(size_t)tn * N_NEUR + col];
        }
    }
}

extern "C" void kernel_launch(void* const* d_in, const int* in_sizes, int n_in,
                              void* d_out, int out_size, void* d_ws, size_t ws_size,
                              hipStream_t stream) {
    const float* x_in   = (const float*)d_in[0];
    const float* w      = (const float*)d_in[1];
    const float* E_L    = (const float*)d_in[2];
    const float* tau_m  = (const float*)d_in[3];
    const float* G      = (const float*)d_in[4];
    const float* R_I    = (const float*)d_in[5];
    const float* f_v    = (const float*)d_in[6];
    const float* f_I    = (const float*)d_in[7];
    const float* dths   = (const float*)d_in[8];
    const float* b_s    = (const float*)d_in[9];
    const float* a_v    = (const float*)d_in[10];
    const float* b_v    = (const float*)d_in[11];
    const float* th_inf = (const float*)d_in[12];
    const float* dV     = (const float*)d_in[13];
    const float* I_A    = (const float*)d_in[14];

    float* out = (float*)d_out;
    ull* buf = (ull*)d_ws;   // 2 parities * 32 copies * 1024 * 8B = 512 KB

    glif_init<<<(2 * PSTRIDE + 255) / 256, 256, 0, stream>>>(buf);
    glif_main<<<NBLK, TPB, 0, stream>>>(x_in, w, E_L, tau_m, G, R_I, f_v, f_I,
                                        dths, b_s, a_v, b_v, th_inf, dV, I_A,
                                        out, buf);
}

// Round 7
// 16654.185 us; speedup vs baseline: 1.0934x; 1.0934x over previous
//
#include <hip/hip_runtime.h>

// GLIF recurrent network: T=8192 sequential steps, N=1024 neurons.
// R4 skeleton (32 blocks x 256 threads, 4 waves, block owns 32 columns):
//   - inline-asm poll: 4 loads issued, 64 dummy FMAs in the load shadow
//     (keeps SIMD issue active / clocks up at zero latency cost), ONE
//     vmcnt(0), check tags.
//   - NO barrier between stage and FMA: each wave's FMA reads only the
//     slice it polled itself (rows [256wv,256wv+256)); wave-local
//     lgkmcnt(0) orders ds_write -> ds_read.
//   - ONE barrier per step (B2) for the cross-wave reduction. red(t+1)
//     write-after-read is safe: a wave passes poll(t+1) only after every
//     remote block published t+1, which transitively requires every local
//     wave's publish(t) (and hence its red(t) reads) to have completed.
//   - phase C on ALL 64 lanes (redundant, deterministic); each lane
//     publishes 4 consumer copies (c = 8*wv + 4*h + k).
// Entry: u64 = (tag=step)<<32 | f32 bits, double-buffered by step parity,
// per-consumer private copies (1 writer + 1 reader block per line).

#define T_STEPS 8192
#define N_NEUR  1024
#define NBLK    32
#define TPB     256
#define PSTRIDE (NBLK * N_NEUR)          // u64 entries per parity (32 copies)

typedef unsigned long long ull;

__global__ void glif_init(ull* __restrict__ buf) {
    int i = blockIdx.x * blockDim.x + threadIdx.x;
    if (i < PSTRIDE) {
        buf[i] = 0ULL;                                // S_0: value 0.0f, tag 0
    } else if (i < 2 * PSTRIDE) {
        buf[i] = 0xFFFFFFFF00000000ULL;               // odd parity: invalid tag
    }
}

__launch_bounds__(TPB, 1)
__global__ void glif_main(const float* __restrict__ x_in,
                          const float* __restrict__ w_p,
                          const float* __restrict__ E_L_p,
                          const float* __restrict__ tau_m_p,
                          const float* __restrict__ G_p,
                          const float* __restrict__ R_I_p,
                          const float* __restrict__ f_v_p,
                          const float* __restrict__ f_I_p,
                          const float* __restrict__ dths_p,
                          const float* __restrict__ b_s_p,
                          const float* __restrict__ a_v_p,
                          const float* __restrict__ b_v_p,
                          const float* __restrict__ th_inf_p,
                          const float* __restrict__ dV_p,
                          const float* __restrict__ I_A_p,
                          float* __restrict__ out,
                          ull* __restrict__ buf) {
    const int tid  = threadIdx.x;
    const int wv   = tid >> 6;                 // wave 0..3
    const int lane = tid & 63;
    const int h    = lane >> 5;                // half 0/1
    const int colL = lane & 31;                // block-local column
    const int col  = blockIdx.x * 32 + colL;   // global column
    const int ibase = wv * 256 + h * 128;      // this lane's 128 FMA rows

    __shared__ float ix[N_NEUR];               // staged I_add (wave-sliced)
    __shared__ float red[4][32];               // per-wave partial sums

    // ---- one-time: 128 w values (rows ibase..+128, column col)
    float wreg[128];
#pragma unroll
    for (int j = 0; j < 128; ++j) {
        int r = ibase + j;
        float wval = w_p[(size_t)r * N_NEUR + col];
        wreg[j] = (r == col) ? 0.0f : wval;    // zero diagonal (self-recurrence)
    }

    // ---- ALL lanes carry the state for their column (8x redundant per col,
    //      bit-identical updates: same inputs, same fixed-order arithmetic)
    const float E_L     = E_L_p[col];
    const float inv_tau = 1.0f / tau_m_p[col];
    const float Gc      = G_p[col];
    const float R_I     = R_I_p[col];
    const float f_v     = f_v_p[col];
    const float om_fI   = 1.0f - f_I_p[col];
    const float dths    = dths_p[col];
    const float om_bs   = 1.0f - b_s_p[col];
    const float a_v     = a_v_p[col];
    const float b_v     = b_v_p[col];
    const float th_inf  = th_inf_p[col];
    const float dV      = dV_p[col];
    const float I_A     = I_A_p[col];

    float v = E_L, th_s = 30.0f, th_v = 1.0f, I_own = 0.0f;
    float xnext = x_in[col];                   // x for t=0

    // busy-work accumulators (issued in the poll-load shadow; keeps the
    // SIMD issuing so the wave doesn't look idle to power management)
    float d0 = 1.0f, d1 = 1.125f, d2 = 1.25f, d3 = 1.375f;

    float* __restrict__ vs_out = out;
    float* __restrict__ sp_out = out + (size_t)T_STEPS * N_NEUR;

    for (int t = 0; t < T_STEPS; ++t) {
        // ---- phase A: poll 4 tagged u64 (private copy). Issue 4 loads,
        // then 64 independent FMAs while they fly, then one vmcnt(0).
        const ull* src = buf + (size_t)(t & 1) * PSTRIDE
                             + (size_t)blockIdx.x * N_NEUR + tid * 4;
        ull u0, u1, u2, u3;
        const unsigned ut = (unsigned)t;
        for (;;) {
            asm volatile(
                "global_load_dwordx2 %0, %4, off sc0 sc1\n\t"
                "global_load_dwordx2 %1, %4, off offset:8 sc0 sc1\n\t"
                "global_load_dwordx2 %2, %4, off offset:16 sc0 sc1\n\t"
                "global_load_dwordx2 %3, %4, off offset:24 sc0 sc1"
                : "=&v"(u0), "=&v"(u1), "=&v"(u2), "=&v"(u3)
                : "v"(src)
                : "memory");
#pragma unroll
            for (int q = 0; q < 16; ++q) {      // 64 fma in the load shadow
                d0 = fmaf(d0, 1.0000001f, 1e-7f);
                d1 = fmaf(d1, 0.9999999f, 1e-7f);
                d2 = fmaf(d2, 1.0000002f, 1e-7f);
                d3 = fmaf(d3, 0.9999998f, 1e-7f);
            }
            __builtin_amdgcn_sched_barrier(0);
            asm volatile("s_waitcnt vmcnt(0)" ::: "memory");
            bool ok = ((unsigned)(u0 >> 32) == ut) & ((unsigned)(u1 >> 32) == ut) &
                      ((unsigned)(u2 >> 32) == ut) & ((unsigned)(u3 >> 32) == ut);
            if (ok) break;
        }
        ((float4*)ix)[tid] = make_float4(__uint_as_float((unsigned)u0),
                                         __uint_as_float((unsigned)u1),
                                         __uint_as_float((unsigned)u2),
                                         __uint_as_float((unsigned)u3));

        // wave-local fence only: this wave's FMA reads only its own slice.
        asm volatile("s_waitcnt lgkmcnt(0)" ::: "memory");
        __builtin_amdgcn_sched_barrier(0);

        // ---- phase B: 128 MACs, 4 independent chains (broadcast LDS reads)
        float s0 = 0.f, s1 = 0.f, s2 = 0.f, s3 = 0.f;
        const float4* q4 = (const float4*)(ix + ibase);
#pragma unroll
        for (int m = 0; m < 32; ++m) {
            float4 q = q4[m];
            s0 = fmaf(wreg[4 * m + 0], q.x, s0);
            s1 = fmaf(wreg[4 * m + 1], q.y, s1);
            s2 = fmaf(wreg[4 * m + 2], q.z, s2);
            s3 = fmaf(wreg[4 * m + 3], q.w, s3);
        }
        float acc = (s0 + s1) + (s2 + s3);
        acc += __shfl_xor(acc, 32, 64);        // fold halves: wave total (all lanes)
        if (lane < 32) red[wv][colL] = acc;

        // B2: the ONLY barrier per step (lgkm-only wait, no vmcnt drain)
        asm volatile("s_waitcnt lgkmcnt(0)" ::: "memory");
        __builtin_amdgcn_s_barrier();
        __builtin_amdgcn_sched_barrier(0);

        // ---- phase C: all 64 lanes, fixed-order sum (bit-identical), publish 1st
        float xt = xnext;
        float I = (red[0][colL] + red[1][colL]) + (red[2][colL] + red[3][colL])
                  + 0.85f * xt;
        float v_next = v + (I * R_I - Gc * (v - E_L)) * inv_tau;
        float thr = th_s + th_v;
        float z = v_next - thr;
        float soft = 1.0f / (1.0f + __expf(-z));   // surrogate spike
        I_own = om_fI * I_own + soft * I_A;

        // publish: lane serves copies c = 8*wv + 4*h + k  (4 stores/lane)
        ull pk = ((ull)(unsigned)(t + 1) << 32) | (ull)__float_as_uint(I_own);
        ull* dst = buf + (size_t)((t + 1) & 1) * PSTRIDE
                       + (size_t)(wv * 8 + h * 4) * N_NEUR + col;
#pragma unroll
        for (int k = 0; k < 4; ++k) {
            __hip_atomic_store(dst + (size_t)k * N_NEUR, pk,
                               __ATOMIC_RELAXED, __HIP_MEMORY_SCOPE_AGENT);
        }

        // state update + outputs + x-prefetch (fire-and-forget)
        bool  sp = (v_next >= thr);                 // hard spike
        float v_reset = E_L + f_v * (v - E_L) - dV;
        float v_new = sp ? v_reset : v_next;
        th_s = om_bs * th_s + (sp ? dths : 0.0f);
        float d_thv = a_v * (v_new - E_L) - b_v * (th_v - th_inf);
        th_v = th_v + (sp ? 0.0f : d_thv);
        v = v_new;

        if (wv == 0) {                              // one writer per output elem
            if (h == 0) {
                __builtin_nontemporal_store(v_new, &vs_out[(size_t)t * N_NEUR + col]);
            } else {
                __builtin_nontemporal_store(soft, &sp_out[(size_t)t * N_NEUR + col]);
            }
        }
        int tn = (t + 1 < T_STEPS) ? (t + 1) : t;
        xnext = x_in[(size_t)tn * N_NEUR + col];
    }

    // keep busy-work live without affecting output
    asm volatile("" :: "v"(d0), "v"(d1), "v"(d2), "v"(d3));
}

extern "C" void kernel_launch(void* const* d_in, const int* in_sizes, int n_in,
                              void* d_out, int out_size, void* d_ws, size_t ws_size,
                              hipStream_t stream) {
    const float* x_in   = (const float*)d_in[0];
    const float* w      = (const float*)d_in[1];
    const float* E_L    = (const float*)d_in[2];
    const float* tau_m  = (const float*)d_in[3];
    const float* G      = (const float*)d_in[4];
    const float* R_I    = (const float*)d_in[5];
    const float* f_v    = (const float*)d_in[6];
    const float* f_I    = (const float*)d_in[7];
    const float* dths   = (const float*)d_in[8];
    const float* b_s    = (const float*)d_in[9];
    const float* a_v    = (const float*)d_in[10];
    const float* b_v    = (const float*)d_in[11];
    const float* th_inf = (const float*)d_in[12];
    const float* dV     = (const float*)d_in[13];
    const float* I_A    = (const float*)d_in[14];

    float* out = (float*)d_out;
    ull* buf = (ull*)d_ws;   // 2 parities * 32 copies * 1024 * 8B = 512 KB

    glif_init<<<(2 * PSTRIDE + 255) / 256, 256, 0, stream>>>(buf);
    glif_main<<<NBLK, TPB, 0, stream>>>(x_in, w, E_L, tau_m, G, R_I, f_v, f_I,
                                        dths, b_s, a_v, b_v, th_inf, dV, I_A,
                                        out, buf);
}